// Round 1
// baseline (19041.298 us; speedup 1.0000x reference)
//
#include <hip/hip_runtime.h>
#include <math.h>

#define HID 64
#define HEADS 8
#define DH 8
#define TT 4
#define RR 6
#define LAYERS 2
#define NTOT 322000

static const int NS[TT]    = {100000, 200000, 20000, 2000};
static const int FEATS[TT] = {334, 512, 128, 128};
static const int RSRC[RR]  = {0, 1, 1, 2, 1, 3};
static const int RDST[RR]  = {1, 0, 2, 1, 3, 1};
static const int ECNT[RR]  = {800000, 800000, 1000000, 1000000, 200000, 200000};

// ---------------- kernels ----------------

__global__ void fill_f(float* __restrict__ p, float v, int n) {
    int i = blockIdx.x * 256 + threadIdx.x;
    if (i < n) p[i] = v;
}

// h = relu(x @ W + b); one block (64 threads) per node row
__global__ void in_proj(const float* __restrict__ x, const float* __restrict__ W,
                        const float* __restrict__ b, float* __restrict__ h, int F) {
    extern __shared__ float xs[];
    int row = blockIdx.x, col = threadIdx.x;
    for (int f = col; f < F; f += 64) xs[f] = x[(size_t)row * F + f];
    __syncthreads();
    float acc = b[col];
    for (int f = 0; f < F; ++f) acc = fmaf(xs[f], W[f * 64 + col], acc);
    h[(size_t)row * 64 + col] = fmaxf(acc, 0.f);
}

// K/Q/V = h @ {KW,QW,VW} + bias; one block per node row
__global__ void qkv_proj(const float* __restrict__ h,
                         const float* __restrict__ KW, const float* __restrict__ Kb,
                         const float* __restrict__ QW, const float* __restrict__ Qb,
                         const float* __restrict__ VW, const float* __restrict__ Vb,
                         float* __restrict__ K, float* __restrict__ Q, float* __restrict__ V) {
    __shared__ float hs[64];
    int row = blockIdx.x, col = threadIdx.x;
    hs[col] = h[(size_t)row * 64 + col];
    __syncthreads();
    float ak = Kb[col], aq = Qb[col], av = Vb[col];
    for (int f = 0; f < 64; ++f) {
        float hv = hs[f];
        ak = fmaf(hv, KW[f * 64 + col], ak);
        aq = fmaf(hv, QW[f * 64 + col], aq);
        av = fmaf(hv, VW[f * 64 + col], av);
    }
    size_t i = (size_t)row * 64 + col;
    K[i] = ak; Q[i] = aq; V[i] = av;
}

// pass A: score[e,h] = (Q[dst]·(K[src]@A_rel))*P*scale ; atomicMax into m (encoded)
__global__ void edge_score(const int* __restrict__ src, const int* __restrict__ dst,
                           const float* __restrict__ K, const float* __restrict__ Q,
                           const float* __restrict__ A, const float* __restrict__ P,
                           float* __restrict__ score, unsigned* __restrict__ mmax, int E) {
    __shared__ float As[HEADS * 64];
    __shared__ float Ps[HEADS];
    for (int i = threadIdx.x; i < HEADS * 64; i += 256) As[i] = A[i];
    if (threadIdx.x < HEADS) Ps[threadIdx.x] = P[threadIdx.x];
    __syncthreads();
    int idx = blockIdx.x * 256 + threadIdx.x;
    int e = idx >> 3, hh = idx & 7;
    if (e >= E) return;
    int s = src[e], d = dst[e];
    const float* kp = K + (size_t)s * 64 + hh * 8;
    const float* qp = Q + (size_t)d * 64 + hh * 8;
    float kv[8], qv[8];
#pragma unroll
    for (int i = 0; i < 8; ++i) { kv[i] = kp[i]; qv[i] = qp[i]; }
    float sc = 0.f;
#pragma unroll
    for (int f = 0; f < 8; ++f) {
        float kf = 0.f;
#pragma unroll
        for (int dd = 0; dd < 8; ++dd) kf = fmaf(kv[dd], As[hh * 64 + dd * 8 + f], kf);
        sc = fmaf(qp[f], kf, sc);
    }
    sc *= Ps[hh] * 0.35355339059327373f;
    score[(size_t)e * 8 + hh] = sc;
    int si = __float_as_int(sc);
    unsigned enc = (si >= 0) ? ((unsigned)si | 0x80000000u) : (unsigned)(~si);
    atomicMax(&mmax[d * 8 + hh], enc);
}

// pass B: ex = exp(score - m[dst]); den[dst] += ex
__global__ void edge_exp(const int* __restrict__ dst, float* __restrict__ score,
                         const unsigned* __restrict__ mmax, float* __restrict__ den, int E8) {
    int idx = blockIdx.x * 256 + threadIdx.x;
    if (idx >= E8) return;
    int e = idx >> 3, hh = idx & 7;
    int d = dst[e];
    unsigned u = mmax[d * 8 + hh];
    int mi = (u & 0x80000000u) ? (int)(u & 0x7fffffffu) : (~(int)u);
    float m = __int_as_float(mi);
    float ex = __expf(score[idx] - m);
    score[idx] = ex;
    atomicAdd(&den[d * 8 + hh], ex);
}

// pass C: out[dst] += (ex/den) * (V[src]@M_rel)
__global__ void edge_msg(const int* __restrict__ src, const int* __restrict__ dst,
                         const float* __restrict__ V, const float* __restrict__ M,
                         const float* __restrict__ score, const float* __restrict__ den,
                         float* __restrict__ out, int E) {
    __shared__ float Ms[HEADS * 64];
    for (int i = threadIdx.x; i < HEADS * 64; i += 256) Ms[i] = M[i];
    __syncthreads();
    int idx = blockIdx.x * 256 + threadIdx.x;
    int e = idx >> 3, hh = idx & 7;
    if (e >= E) return;
    int s = src[e], d = dst[e];
    float alpha = score[(size_t)e * 8 + hh] / den[d * 8 + hh];
    const float* vp = V + (size_t)s * 64 + hh * 8;
    float vv[8];
#pragma unroll
    for (int i = 0; i < 8; ++i) vv[i] = vp[i];
#pragma unroll
    for (int f = 0; f < 8; ++f) {
        float vf = 0.f;
#pragma unroll
        for (int dd = 0; dd < 8; ++dd) vf = fmaf(vv[dd], Ms[hh * 64 + dd * 8 + f], vf);
        atomicAdd(&out[(size_t)d * 64 + hh * 8 + f], alpha * vf);
    }
}

// h = g * (gelu(out) @ AW + Ab) + (1-g) * h  (in place on h)
__global__ void attn_out(const float* __restrict__ outb, const float* __restrict__ AW,
                         const float* __restrict__ Ab, const float* __restrict__ skip,
                         int lt, float* __restrict__ h) {
    __shared__ float gs[64];
    int row = blockIdx.x, col = threadIdx.x;
    float xv = outb[(size_t)row * 64 + col];
    gs[col] = 0.5f * xv * (1.f + erff(xv * 0.7071067811865475f));
    __syncthreads();
    float acc = Ab[col];
    for (int f = 0; f < 64; ++f) acc = fmaf(gs[f], AW[f * 64 + col], acc);
    float g = 1.f / (1.f + __expf(-skip[lt]));
    size_t i = (size_t)row * 64 + col;
    h[i] = g * acc + (1.f - g) * h[i];
}

// logits = h @ W_out + b_out ; one thread per (node, out-col)
__global__ void out_proj(const float* __restrict__ h, const float* __restrict__ W,
                         const float* __restrict__ b, float* __restrict__ out, int n4) {
    int idx = blockIdx.x * 256 + threadIdx.x;
    if (idx >= n4) return;
    int row = idx >> 2, c = idx & 3;
    float acc = b[c];
    const float* hp = h + (size_t)row * 64;
    for (int f = 0; f < 64; ++f) acc = fmaf(hp[f], W[f * 4 + c], acc);
    out[idx] = acc;
}

// ---------------- launch ----------------

extern "C" void kernel_launch(void* const* d_in, const int* in_sizes, int n_in,
                              void* d_out, int out_size, void* d_ws, size_t ws_size,
                              hipStream_t stream) {
    const float* x[TT]    = {(const float*)d_in[0], (const float*)d_in[1],
                             (const float*)d_in[2], (const float*)d_in[3]};
    const float* Win[TT]  = {(const float*)d_in[4], (const float*)d_in[6],
                             (const float*)d_in[8], (const float*)d_in[10]};
    const float* bin[TT]  = {(const float*)d_in[5], (const float*)d_in[7],
                             (const float*)d_in[9], (const float*)d_in[11]};
    const float* KW = (const float*)d_in[12];
    const float* QW = (const float*)d_in[13];
    const float* VW = (const float*)d_in[14];
    const float* AW = (const float*)d_in[15];
    const float* Kb = (const float*)d_in[16];
    const float* Qb = (const float*)d_in[17];
    const float* Vb = (const float*)d_in[18];
    const float* Ab = (const float*)d_in[19];
    const float* skip  = (const float*)d_in[20];
    const float* A_rel = (const float*)d_in[21];
    const float* M_rel = (const float*)d_in[22];
    const float* P_rel = (const float*)d_in[23];
    const float* W_out = (const float*)d_in[24];
    const float* b_out = (const float*)d_in[25];
    const int* ei[RR] = {(const int*)d_in[26], (const int*)d_in[27], (const int*)d_in[28],
                         (const int*)d_in[29], (const int*)d_in[30], (const int*)d_in[31]};

    float* ws = (float*)d_ws;
    size_t off = 0;
    float* h   = ws + off; off += (size_t)NTOT * 64;
    float* K   = ws + off; off += (size_t)NTOT * 64;
    float* Q   = ws + off; off += (size_t)NTOT * 64;
    float* V   = ws + off; off += (size_t)NTOT * 64;
    float* outb = ws + off; off += (size_t)NTOT * 64;
    float* score = ws + off; off += (size_t)1000000 * 8;
    float* den = ws + off; off += (size_t)200000 * 8;
    unsigned* mmax = (unsigned*)(ws + off); off += (size_t)200000 * 8;

    int nodeOff[TT] = {0, 100000, 300000, 320000};

    // input projections
    for (int t = 0; t < TT; ++t) {
        in_proj<<<NS[t], 64, FEATS[t] * sizeof(float), stream>>>(
            x[t], Win[t], bin[t], h + (size_t)nodeOff[t] * 64, FEATS[t]);
    }

    for (int l = 0; l < LAYERS; ++l) {
        // K/Q/V projections
        for (int t = 0; t < TT; ++t) {
            size_t wOff = (size_t)(l * TT + t) * 64 * 64;
            size_t bOff = (size_t)(l * TT + t) * 64;
            size_t nOff = (size_t)nodeOff[t] * 64;
            qkv_proj<<<NS[t], 64, 0, stream>>>(
                h + nOff, KW + wOff, Kb + bOff, QW + wOff, Qb + bOff,
                VW + wOff, Vb + bOff, K + nOff, Q + nOff, V + nOff);
        }
        // zero attention output accumulator
        fill_f<<<((size_t)NTOT * 64 + 255) / 256, 256, 0, stream>>>(outb, 0.f, NTOT * 64);

        for (int r = 0; r < RR; ++r) {
            int s = RSRC[r], d = RDST[r], E = ECNT[r];
            const int* srcIdx = ei[r];
            const int* dstIdx = ei[r] + E;
            int nd8 = NS[d] * 8;
            // zero den and mmax (encoded -inf == 0)
            fill_f<<<(2 * nd8 + 255) / 256, 256, 0, stream>>>(den, 0.f, 2 * nd8);
            const float* Ar = A_rel + (size_t)(l * RR + r) * HEADS * 64;
            const float* Mr = M_rel + (size_t)(l * RR + r) * HEADS * 64;
            const float* Pr = P_rel + (size_t)(l * RR + r) * HEADS;
            const float* Ksrc = K + (size_t)nodeOff[s] * 64;
            const float* Qdst = Q + (size_t)nodeOff[d] * 64;
            const float* Vsrc = V + (size_t)nodeOff[s] * 64;
            float* outd = outb + (size_t)nodeOff[d] * 64;
            int grid = (E * 8 + 255) / 256;
            edge_score<<<grid, 256, 0, stream>>>(srcIdx, dstIdx, Ksrc, Qdst, Ar, Pr,
                                                 score, mmax, E);
            edge_exp<<<grid, 256, 0, stream>>>(dstIdx, score, mmax, den, E * 8);
            edge_msg<<<grid, 256, 0, stream>>>(srcIdx, dstIdx, Vsrc, Mr, score, den,
                                               outd, E);
        }
        // output transform + gated skip (in place on h)
        for (int t = 0; t < TT; ++t) {
            size_t wOff = (size_t)(l * TT + t) * 64 * 64;
            size_t bOff = (size_t)(l * TT + t) * 64;
            size_t nOff = (size_t)nodeOff[t] * 64;
            attn_out<<<NS[t], 64, 0, stream>>>(outb + nOff, AW + wOff, Ab + bOff,
                                               skip, l * TT + t, h + nOff);
        }
    }

    // final projection (author nodes)
    out_proj<<<(NS[0] * 4 + 255) / 256, 256, 0, stream>>>(h, W_out, b_out,
                                                          (float*)d_out, NS[0] * 4);
}

// Round 3
// 5437.978 us; speedup vs baseline: 3.5015x; 3.5015x over previous
//
#include <hip/hip_runtime.h>
#include <math.h>

#define HID 64
#define HEADS 8
#define DH 8
#define TT 4
#define RR 6
#define LAYERS 2
#define NTOT 322000

static const int NS[TT]    = {100000, 200000, 20000, 2000};
static const int FEATS[TT] = {334, 512, 128, 128};
static const int RSRC[RR]  = {0, 1, 1, 2, 1, 3};
static const int RDST[RR]  = {1, 0, 2, 1, 3, 1};

// ---------------- utility ----------------

__global__ void fill_f(float* __restrict__ p, float v, int n) {
    int i = blockIdx.x * 256 + threadIdx.x;
    if (i < n) p[i] = v;
}

__global__ void fill_i(int* __restrict__ p, int v, int n) {
    int i = blockIdx.x * 256 + threadIdx.x;
    if (i < n) p[i] = v;
}

// ---------------- node-level GEMM-ish kernels ----------------

// h = relu(x @ W + b); one block (64 threads) per node row
__global__ void in_proj(const float* __restrict__ x, const float* __restrict__ W,
                        const float* __restrict__ b, float* __restrict__ h, int F) {
    extern __shared__ float xs[];
    int row = blockIdx.x, col = threadIdx.x;
    for (int f = col; f < F; f += 64) xs[f] = x[(size_t)row * F + f];
    __syncthreads();
    float acc = b[col];
    for (int f = 0; f < F; ++f) acc = fmaf(xs[f], W[f * 64 + col], acc);
    h[(size_t)row * 64 + col] = fmaxf(acc, 0.f);
}

// K/Q/V = h @ {KW,QW,VW} + bias; one block per node row
__global__ void qkv_proj(const float* __restrict__ h,
                         const float* __restrict__ KW, const float* __restrict__ Kb,
                         const float* __restrict__ QW, const float* __restrict__ Qb,
                         const float* __restrict__ VW, const float* __restrict__ Vb,
                         float* __restrict__ K, float* __restrict__ Q, float* __restrict__ V) {
    __shared__ float hs[64];
    int row = blockIdx.x, col = threadIdx.x;
    hs[col] = h[(size_t)row * 64 + col];
    __syncthreads();
    float ak = Kb[col], aq = Qb[col], av = Vb[col];
    for (int f = 0; f < 64; ++f) {
        float hv = hs[f];
        ak = fmaf(hv, KW[f * 64 + col], ak);
        aq = fmaf(hv, QW[f * 64 + col], aq);
        av = fmaf(hv, VW[f * 64 + col], av);
    }
    size_t i = (size_t)row * 64 + col;
    K[i] = ak; Q[i] = aq; V[i] = av;
}

// h = g * (gelu(out) @ AW + Ab) + (1-g) * h  (in place on h)
__global__ void attn_out(const float* __restrict__ outb, const float* __restrict__ AW,
                         const float* __restrict__ Ab, const float* __restrict__ skip,
                         int lt, float* __restrict__ h) {
    __shared__ float gs[64];
    int row = blockIdx.x, col = threadIdx.x;
    float xv = outb[(size_t)row * 64 + col];
    gs[col] = 0.5f * xv * (1.f + erff(xv * 0.7071067811865475f));
    __syncthreads();
    float acc = Ab[col];
    for (int f = 0; f < 64; ++f) acc = fmaf(gs[f], AW[f * 64 + col], acc);
    float g = 1.f / (1.f + __expf(-skip[lt]));
    size_t i = (size_t)row * 64 + col;
    h[i] = g * acc + (1.f - g) * h[i];
}

// logits = h @ W_out + b_out
__global__ void out_proj(const float* __restrict__ h, const float* __restrict__ W,
                         const float* __restrict__ b, float* __restrict__ out, int n4) {
    int idx = blockIdx.x * 256 + threadIdx.x;
    if (idx >= n4) return;
    int row = idx >> 2, c = idx & 3;
    float acc = b[c];
    const float* hp = h + (size_t)row * 64;
    for (int f = 0; f < 64; ++f) acc = fmaf(hp[f], W[f * 4 + c], acc);
    out[idx] = acc;
}

// ---------------- CSR build ----------------

__global__ void hist_k(const int* __restrict__ dst, int* __restrict__ deg, int E) {
    int i = blockIdx.x * 256 + threadIdx.x;
    if (i < E) atomicAdd(&deg[dst[i]], 1);
}

// per-block sums over chunks of 1024
__global__ void scan1(const int* __restrict__ deg, int* __restrict__ bsum, int n) {
    __shared__ int sdata[256];
    int tid = threadIdx.x;
    int base = blockIdx.x * 1024 + tid * 4;
    int s = 0;
#pragma unroll
    for (int j = 0; j < 4; ++j) if (base + j < n) s += deg[base + j];
    sdata[tid] = s;
    __syncthreads();
    for (int off = 128; off > 0; off >>= 1) {
        if (tid < off) sdata[tid] += sdata[tid + off];
        __syncthreads();
    }
    if (tid == 0) bsum[blockIdx.x] = sdata[0];
}

// serial exclusive scan of block sums (nb <= ~200)
__global__ void scan2(int* __restrict__ bsum, int nb) {
    if (blockIdx.x == 0 && threadIdx.x == 0) {
        int run = 0;
        for (int i = 0; i < nb; ++i) { int t = bsum[i]; bsum[i] = run; run += t; }
    }
}

// write exclusive prefix into row_ptr
__global__ void scan3(const int* __restrict__ deg, const int* __restrict__ bsum,
                      int* __restrict__ rp, int n, int E) {
    __shared__ int sc[256];
    int tid = threadIdx.x;
    int base = blockIdx.x * 1024 + tid * 4;
    int v0 = 0, v1 = 0, v2 = 0, v3 = 0;
    if (base + 0 < n) v0 = deg[base + 0];
    if (base + 1 < n) v1 = deg[base + 1];
    if (base + 2 < n) v2 = deg[base + 2];
    if (base + 3 < n) v3 = deg[base + 3];
    int s = v0 + v1 + v2 + v3;
    sc[tid] = s;
    __syncthreads();
    for (int off = 1; off < 256; off <<= 1) {
        int t = (tid >= off) ? sc[tid - off] : 0;
        __syncthreads();
        sc[tid] += t;
        __syncthreads();
    }
    int run = bsum[blockIdx.x] + sc[tid] - s;   // exclusive prefix
    if (base + 0 < n) { rp[base + 0] = run; run += v0; }
    if (base + 1 < n) { rp[base + 1] = run; run += v1; }
    if (base + 2 < n) { rp[base + 2] = run; run += v2; }
    if (base + 3 < n) { rp[base + 3] = run; run += v3; }
    if (blockIdx.x == 0 && tid == 0) rp[n] = E;
}

__global__ void scatter_k(const int* __restrict__ src, const int* __restrict__ dst,
                          const int* __restrict__ rp, int* __restrict__ cnt,
                          int* __restrict__ col, int E) {
    int i = blockIdx.x * 256 + threadIdx.x;
    if (i >= E) return;
    int d = dst[i];
    int p = rp[d] + atomicAdd(&cnt[d], 1);
    col[p] = src[i];
}

// ---------------- fused per-relation attention ----------------
// One wave (64 lanes) per destination node; lane = head*8 + dim.
// score_e = k_e . qhat, qhat = (A_rel^T q) * P * scale (per node)
// accumulate sum(alpha*v) raw; apply M_rel once in epilogue.
__global__ __launch_bounds__(256) void rel_attn(
    const int* __restrict__ row_ptr, const int* __restrict__ col,
    const float* __restrict__ K, const float* __restrict__ Q, const float* __restrict__ V,
    const float* __restrict__ A, const float* __restrict__ M, const float* __restrict__ P,
    float* __restrict__ outb, int Nd)
{
    __shared__ float As[512], Ms[512], Ps[8];
    int tid = threadIdx.x;
    for (int i = tid; i < 512; i += 256) { As[i] = A[i]; Ms[i] = M[i]; }
    if (tid < 8) Ps[tid] = P[tid];
    __syncthreads();
    int wave = tid >> 6, lane = tid & 63;
    int d = blockIdx.x * 4 + wave;
    if (d >= Nd) return;
    int hh = lane >> 3, ff = lane & 7;
    int gbase = lane & 56;

    float q = Q[(size_t)d * 64 + lane];
    // qhat[hh,dd]  (this lane's dd == ff) = sum_f A[hh,dd,f] * q[hh,f]
    float qhat = 0.f;
#pragma unroll
    for (int f = 0; f < 8; ++f)
        qhat = fmaf(__shfl(q, gbase + f, 64), As[hh * 64 + ff * 8 + f], qhat);
    qhat *= Ps[hh] * 0.35355339059327373f;

    int e0 = row_ptr[d], e1 = row_ptr[d + 1];
    float m = -INFINITY, lsum = 0.f, acc = 0.f;
    for (int e = e0; e < e1; ++e) {
        int s = col[e];
        float kv = K[(size_t)s * 64 + lane];
        float vv = V[(size_t)s * 64 + lane];
        float p = kv * qhat;
        p += __shfl_xor(p, 1, 64);
        p += __shfl_xor(p, 2, 64);
        p += __shfl_xor(p, 4, 64);        // p = score for this head (all 8 lanes agree)
        float mn = fmaxf(m, p);
        float aa = __expf(m - mn);
        float w  = __expf(p - mn);
        lsum = lsum * aa + w;
        acc  = acc * aa + w * vv;
        m = mn;
    }
    // o[hh,ff] = sum_dd acc[hh,dd] * M[hh,dd,ff]
    float o = 0.f;
#pragma unroll
    for (int dd = 0; dd < 8; ++dd)
        o = fmaf(__shfl(acc, gbase + dd, 64), Ms[hh * 64 + dd * 8 + ff], o);
    float inv = (lsum > 0.f) ? 1.f / lsum : 0.f;
    outb[(size_t)d * 64 + lane] += o * inv;
}

// ---------------- launch ----------------

extern "C" void kernel_launch(void* const* d_in, const int* in_sizes, int n_in,
                              void* d_out, int out_size, void* d_ws, size_t ws_size,
                              hipStream_t stream) {
    const float* x[TT]    = {(const float*)d_in[0], (const float*)d_in[1],
                             (const float*)d_in[2], (const float*)d_in[3]};
    const float* Win[TT]  = {(const float*)d_in[4], (const float*)d_in[6],
                             (const float*)d_in[8], (const float*)d_in[10]};
    const float* bin[TT]  = {(const float*)d_in[5], (const float*)d_in[7],
                             (const float*)d_in[9], (const float*)d_in[11]};
    const float* KW = (const float*)d_in[12];
    const float* QW = (const float*)d_in[13];
    const float* VW = (const float*)d_in[14];
    const float* AW = (const float*)d_in[15];
    const float* Kb = (const float*)d_in[16];
    const float* Qb = (const float*)d_in[17];
    const float* Vb = (const float*)d_in[18];
    const float* Ab = (const float*)d_in[19];
    const float* skip  = (const float*)d_in[20];
    const float* A_rel = (const float*)d_in[21];
    const float* M_rel = (const float*)d_in[22];
    const float* P_rel = (const float*)d_in[23];
    const float* W_out = (const float*)d_in[24];
    const float* b_out = (const float*)d_in[25];
    const int* ei[RR] = {(const int*)d_in[26], (const int*)d_in[27], (const int*)d_in[28],
                         (const int*)d_in[29], (const int*)d_in[30], (const int*)d_in[31]};
    int E[RR];
    for (int r = 0; r < RR; ++r) E[r] = in_sizes[26 + r] / 2;

    float* ws = (float*)d_ws;
    size_t off = 0;
    float* h    = ws + off; off += (size_t)NTOT * 64;
    float* K    = ws + off; off += (size_t)NTOT * 64;
    float* Q    = ws + off; off += (size_t)NTOT * 64;
    float* V    = ws + off; off += (size_t)NTOT * 64;
    float* outb = ws + off; off += (size_t)NTOT * 64;
    int* ibase = (int*)(ws + off);
    size_t ioff = 0;
    int* col_all = ibase + ioff;               // 4M total
    int colOff[RR]; int acc_e = 0;
    for (int r = 0; r < RR; ++r) { colOff[r] = acc_e; acc_e += E[r]; }
    ioff += (size_t)acc_e;
    int* rp_all = ibase + ioff;
    int rpOff[RR]; int acc_rp = 0;
    for (int r = 0; r < RR; ++r) { rpOff[r] = acc_rp; acc_rp += NS[RDST[r]] + 1; }
    ioff += (size_t)acc_rp;
    int* deg  = ibase + ioff; ioff += 200000;
    int* cnt  = ibase + ioff; ioff += 200000;
    int* bsum = ibase + ioff; ioff += 256;

    int nodeOff[TT] = {0, 100000, 300000, 320000};

    // ---- CSR build (edge lists identical for both layers) ----
    for (int r = 0; r < RR; ++r) {
        int Nd = NS[RDST[r]];
        const int* srcIdx = ei[r];
        const int* dstIdx = ei[r] + E[r];
        int* rp  = rp_all + rpOff[r];
        int* col = col_all + colOff[r];
        // BUGFIX (R2 crash): deg and cnt are at fixed offsets 200000 apart;
        // zero each explicitly for THIS relation's Nd, every relation.
        fill_i<<<(Nd + 255) / 256, 256, 0, stream>>>(deg, 0, Nd);
        fill_i<<<(Nd + 255) / 256, 256, 0, stream>>>(cnt, 0, Nd);
        hist_k<<<(E[r] + 255) / 256, 256, 0, stream>>>(dstIdx, deg, E[r]);
        int nb = (Nd + 1023) / 1024;
        scan1<<<nb, 256, 0, stream>>>(deg, bsum, Nd);
        scan2<<<1, 64, 0, stream>>>(bsum, nb);
        scan3<<<nb, 256, 0, stream>>>(deg, bsum, rp, Nd, E[r]);
        scatter_k<<<(E[r] + 255) / 256, 256, 0, stream>>>(srcIdx, dstIdx, rp, cnt, col, E[r]);
    }

    // ---- input projections ----
    for (int t = 0; t < TT; ++t) {
        in_proj<<<NS[t], 64, FEATS[t] * sizeof(float), stream>>>(
            x[t], Win[t], bin[t], h + (size_t)nodeOff[t] * 64, FEATS[t]);
    }

    for (int l = 0; l < LAYERS; ++l) {
        for (int t = 0; t < TT; ++t) {
            size_t wOff = (size_t)(l * TT + t) * 64 * 64;
            size_t bOff = (size_t)(l * TT + t) * 64;
            size_t nOff = (size_t)nodeOff[t] * 64;
            qkv_proj<<<NS[t], 64, 0, stream>>>(
                h + nOff, KW + wOff, Kb + bOff, QW + wOff, Qb + bOff,
                VW + wOff, Vb + bOff, K + nOff, Q + nOff, V + nOff);
        }
        fill_f<<<((size_t)NTOT * 64 + 255) / 256, 256, 0, stream>>>(outb, 0.f, NTOT * 64);

        for (int r = 0; r < RR; ++r) {
            int s = RSRC[r], d = RDST[r];
            int Nd = NS[d];
            const float* Ar = A_rel + (size_t)(l * RR + r) * HEADS * 64;
            const float* Mr = M_rel + (size_t)(l * RR + r) * HEADS * 64;
            const float* Pr = P_rel + (size_t)(l * RR + r) * HEADS;
            rel_attn<<<(Nd + 3) / 4, 256, 0, stream>>>(
                rp_all + rpOff[r], col_all + colOff[r],
                K + (size_t)nodeOff[s] * 64, Q + (size_t)nodeOff[d] * 64,
                V + (size_t)nodeOff[s] * 64, Ar, Mr, Pr,
                outb + (size_t)nodeOff[d] * 64, Nd);
        }
        for (int t = 0; t < TT; ++t) {
            size_t wOff = (size_t)(l * TT + t) * 64 * 64;
            size_t bOff = (size_t)(l * TT + t) * 64;
            size_t nOff = (size_t)nodeOff[t] * 64;
            attn_out<<<NS[t], 64, 0, stream>>>(outb + nOff, AW + wOff, Ab + bOff,
                                               skip, l * TT + t, h + nOff);
        }
    }

    out_proj<<<(NS[0] * 4 + 255) / 256, 256, 0, stream>>>(h, W_out, b_out,
                                                          (float*)d_out, NS[0] * 4);
}